// Round 10
// baseline (1169.574 us; speedup 1.0000x reference)
//
#include <hip/hip_runtime.h>
#include <hip/hip_bf16.h>
#include <math.h>

#define D_MODEL 256
#define NH 8
#define DFF 1024
#define NLAYERS 6
#define B_ 8
#define L_ 1024
#define NR (B_*L_)          // 8192 rows
#define TOPK 256            // L/4
#define LNEPS 1e-5f

typedef __attribute__((ext_vector_type(8))) short bf16x8;
typedef __attribute__((ext_vector_type(4))) float f32x4;

// ---------------- helpers ----------------
__device__ __forceinline__ float wsum(float v){
  #pragma unroll
  for(int o=32;o>0;o>>=1) v += __shfl_xor(v,o,64);
  return v;
}
__device__ __forceinline__ short f2bf(float x){
  unsigned u = __float_as_uint(x);
  u += 0x7fffu + ((u>>16)&1u);   // RNE (finite inputs only)
  return (short)(u>>16);
}
__device__ __forceinline__ float bf2f(short s){
  return __uint_as_float(((unsigned)(unsigned short)s)<<16);
}
// packed 2x f32 -> 2x bf16 (v_cvt_pk_bf16_f32)
__device__ __forceinline__ unsigned pk2bf(float a, float b){
  __hip_bfloat162 h = __float22bfloat162_rn(make_float2(a,b));
  unsigned u; __builtin_memcpy(&u, &h, 4);
  return u;
}
// sortable 16-bit key -> float value (uniform use -> SALU)
__device__ __forceinline__ float kinvf(int k){
  unsigned u = (k & 0x8000) ? ((unsigned)k ^ 0x8000u) : ((unsigned)k ^ 0xFFFFu);
  return __uint_as_float(u << 16);
}
// async global->LDS, 16B per lane (dest = wave-uniform base + lane*16)
__device__ __forceinline__ void g2l(const short* g, short* l){
  __builtin_amdgcn_global_load_lds(
      (const __attribute__((address_space(1))) unsigned int*)g,
      (__attribute__((address_space(3))) unsigned int*)l,
      16, 0, 0);
}

// ---------------- embed: h = x@in_w + in_b + pe ----------------
__global__ __launch_bounds__(256) void embed_kernel(
    const float* __restrict__ x, const float* __restrict__ in_w,
    const float* __restrict__ in_b, float* __restrict__ h)
{
  int tid = blockIdx.x*256 + threadIdx.x;
  int n  = tid >> 6;
  int d0 = (tid & 63) << 2;
  int l  = n & (L_-1);
  float x0 = x[2*n], x1 = x[2*n+1];
  const float kf = -0.07195578415606394f;   // -ln(10000)/128
  float pe[4];
  #pragma unroll
  for(int ii=0; ii<2; ++ii){
    int i = (d0>>1) + ii;
    float dv  = expf((float)i * kf);
    float ang = (float)l * dv;
    pe[2*ii]   = sinf(ang);
    pe[2*ii+1] = cosf(ang);
  }
  float4 w0 = *(const float4*)(in_w + d0);
  float4 w1 = *(const float4*)(in_w + D_MODEL + d0);
  float4 bb = *(const float4*)(in_b + d0);
  float4 o;
  o.x = x0*w0.x + x1*w1.x + bb.x + pe[0];
  o.y = x0*w0.y + x1*w1.y + bb.y + pe[1];
  o.z = x0*w0.z + x1*w1.z + bb.z + pe[2];
  o.w = x0*w0.w + x1*w1.w + bb.w + pe[3];
  *(float4*)(h + (size_t)n*D_MODEL + d0) = o;
}

// ---------------- weight convert+transpose: WT[n][k] = bf16(W[k][n]) ----------------
__global__ __launch_bounds__(256) void wcvt(
    const float* __restrict__ W, short* __restrict__ WT, int N, int kshift)
{
  int idx = blockIdx.x*256 + threadIdx.x;
  int K = 1<<kshift;
  if (idx >= N*K) return;
  int n = idx >> kshift, k = idx & (K-1);
  WT[idx] = f2bf(W[(size_t)k*N + n]);
}

// ---------------- LayerNorm: wave per row ----------------
// OM: 0 = fp32 out, 2 = bf16 out only
template<int OM>
__global__ __launch_bounds__(256) void ln_kernel(
    const float* __restrict__ in, const float* __restrict__ g,
    const float* __restrict__ b, float* __restrict__ out,
    short* __restrict__ outb)
{
  int wave = threadIdx.x >> 6, lane = threadIdx.x & 63;
  int row = blockIdx.x*4 + wave;
  float4 v = ((const float4*)(in + (size_t)row*D_MODEL))[lane];
  float s  = v.x+v.y+v.z+v.w;
  float sq = v.x*v.x+v.y*v.y+v.z*v.z+v.w*v.w;
  s = wsum(s); sq = wsum(sq);
  float mean = s*(1.f/D_MODEL);
  float var  = sq*(1.f/D_MODEL) - mean*mean;
  float rstd = 1.f/sqrtf(var + LNEPS);
  float4 gv = ((const float4*)g)[lane];
  float4 bv = ((const float4*)b)[lane];
  float4 o;
  o.x = (v.x-mean)*rstd*gv.x + bv.x;
  o.y = (v.y-mean)*rstd*gv.y + bv.y;
  o.z = (v.z-mean)*rstd*gv.z + bv.z;
  o.w = (v.w-mean)*rstd*gv.w + bv.w;
  if (OM == 0){
    ((float4*)(out + (size_t)row*D_MODEL))[lane] = o;
  }
  if (OM == 2){
    uint2 pk; pk.x = pk2bf(o.x, o.y); pk.y = pk2bf(o.z, o.w);
    *(uint2*)(outb + (size_t)row*D_MODEL + lane*4) = pk;
  }
}

// ---------------- fused: h += LN_a(tb); s2b = bf16(LN_2(h)) ----------------
__global__ __launch_bounds__(256) void lnln_kernel(
    const float* __restrict__ tb,
    const float* __restrict__ ga, const float* __restrict__ ba,
    const float* __restrict__ g2, const float* __restrict__ b2,
    float* __restrict__ h, short* __restrict__ s2b)
{
  int wave = threadIdx.x >> 6, lane = threadIdx.x & 63;
  int row = blockIdx.x*4 + wave;
  float4 v = ((const float4*)(tb + (size_t)row*D_MODEL))[lane];
  float s  = v.x+v.y+v.z+v.w;
  float sq = v.x*v.x+v.y*v.y+v.z*v.z+v.w*v.w;
  s = wsum(s); sq = wsum(sq);
  float mean = s*(1.f/D_MODEL);
  float var  = sq*(1.f/D_MODEL) - mean*mean;
  float rstd = 1.f/sqrtf(var + LNEPS);
  float4 gv = ((const float4*)ga)[lane];
  float4 bv = ((const float4*)ba)[lane];
  float4* hp = (float4*)(h + (size_t)row*D_MODEL) + lane;
  float4 hv = *hp;
  float4 hn;
  hn.x = hv.x + (v.x-mean)*rstd*gv.x + bv.x;
  hn.y = hv.y + (v.y-mean)*rstd*gv.y + bv.y;
  hn.z = hv.z + (v.z-mean)*rstd*gv.z + bv.z;
  hn.w = hv.w + (v.w-mean)*rstd*gv.w + bv.w;
  *hp = hn;
  float s2  = hn.x+hn.y+hn.z+hn.w;
  float sq2 = hn.x*hn.x+hn.y*hn.y+hn.z*hn.z+hn.w*hn.w;
  s2 = wsum(s2); sq2 = wsum(sq2);
  float m2 = s2*(1.f/D_MODEL);
  float v2 = sq2*(1.f/D_MODEL) - m2*m2;
  float r2 = 1.f/sqrtf(v2 + LNEPS);
  float4 g2v = ((const float4*)g2)[lane];
  float4 b2v = ((const float4*)b2)[lane];
  uint2 pk;
  pk.x = pk2bf((hn.x-m2)*r2*g2v.x + b2v.x, (hn.y-m2)*r2*g2v.y + b2v.y);
  pk.y = pk2bf((hn.z-m2)*r2*g2v.z + b2v.z, (hn.w-m2)*r2*g2v.w + b2v.w);
  *(uint2*)(s2b + (size_t)row*D_MODEL + lane*4) = pk;
}

// ---------------- bf16 MFMA GEMM: 128x64 tile, BK=32 (measured-best) ----------------
// MODE 0: qkv epilogue (Q/K row-major bf16 + V^T bf16)
// MODE 1: Cf = acc + bias + bf2f(residb)    (fp32 out)
// MODE 3: Cf += acc + bias; BT batch-indexed by m0>>10 (ff2 w/ scaled W2)
// MODE 4: Cb = bf16(acc + bias) + per-column sum/sumsq partials (ff1)
template<int MODE>
__global__ __launch_bounds__(256) void mfma_gemm(
    const short* __restrict__ A, const short* __restrict__ BT,
    const float* __restrict__ bias, const short* __restrict__ residb,
    float* __restrict__ Cf, short* __restrict__ Cb, short* __restrict__ Vt,
    float* __restrict__ psum, float* __restrict__ psq,
    int N, int K)
{
  __shared__ __align__(16) short As[128*32];   // 8 KB [m][k]
  __shared__ __align__(16) short Bs[64*32];    // 4 KB [n][k]
  const int t = threadIdx.x, wv = t>>6, lane = t&63;
  const int r16 = lane&15, quad = lane>>4;
  const int m0 = blockIdx.y*128, n0 = blockIdx.x*64;
  const int ia0 = wv*128 + lane, ia1 = ia0 + 64;
  const int ib  = wv*64 + lane;
  const short* Ab = A  + (size_t)m0*K;
  const short* Bb = BT + (size_t)n0*K;
  if (MODE == 3) Bb += (size_t)(m0>>10)*262144;   // per-batch scaled W2
  const f32x4 z = {0.f,0.f,0.f,0.f};
  f32x4 acc[2][4];
  #pragma unroll
  for (int i=0;i<2;++i)
    #pragma unroll
    for (int j=0;j<4;++j) acc[i][j] = z;

  for (int k0 = 0; k0 < K; k0 += 32){
    __syncthreads();
    g2l(Ab + (size_t)(ia0>>2)*K + k0 + (ia0&3)*8, As + ia0*8);
    g2l(Ab + (size_t)(ia1>>2)*K + k0 + (ia1&3)*8, As + ia1*8);
    g2l(Bb + (size_t)(ib>>2)*K  + k0 + (ib&3)*8,  Bs + ib*8);
    __syncthreads();
    bf16x8 af0 = *(const bf16x8*)(As + ((wv*32      + r16)*32 + quad*8));
    bf16x8 af1 = *(const bf16x8*)(As + ((wv*32 + 16 + r16)*32 + quad*8));
    bf16x8 bf[4];
    #pragma unroll
    for (int ct=0; ct<4; ++ct)
      bf[ct] = *(const bf16x8*)(Bs + ((ct*16 + r16)*32 + quad*8));
    #pragma unroll
    for (int ct=0; ct<4; ++ct){
      acc[0][ct] = __builtin_amdgcn_mfma_f32_16x16x32_bf16(af0, bf[ct], acc[0][ct], 0,0,0);
      acc[1][ct] = __builtin_amdgcn_mfma_f32_16x16x32_bf16(af1, bf[ct], acc[1][ct], 0,0,0);
    }
  }

  float cs[4] = {0.f,0.f,0.f,0.f}, cq[4] = {0.f,0.f,0.f,0.f};
  #pragma unroll
  for (int rt=0; rt<2; ++rt){
    const int mb = m0 + wv*32 + rt*16 + quad*4;
    #pragma unroll
    for (int ct=0; ct<4; ++ct){
      const int n = n0 + ct*16 + r16;
      const float bv = bias[n];
      if (MODE == 0){
        if (n < 512){                    // Q or K: qkbf[region*64+bh][l][d]
          int region = n>>8, hh = (n>>5)&7, d = n&31;
          #pragma unroll
          for (int r=0;r<4;++r){
            int l = mb + r;
            size_t base = (((size_t)(region*64 + (l>>10)*8 + hh))*1024 + (l&1023))*32 + d;
            Cb[base] = f2bf(acc[rt][ct][r] + bv);
          }
        } else {                         // V transposed: vT[bh][d][l]
          int dv = n - 512, hh = dv>>5, d = dv&31;
          int b = mb>>10, lloc = mb&1023;
          size_t base = (((size_t)(b*8 + hh))*32 + d)*1024 + lloc;
          uint2 pk;
          pk.x = pk2bf(acc[rt][ct][0] + bv, acc[rt][ct][1] + bv);
          pk.y = pk2bf(acc[rt][ct][2] + bv, acc[rt][ct][3] + bv);
          *(uint2*)(Vt + base) = pk;
        }
      } else {
        #pragma unroll
        for (int r=0;r<4;++r){
          size_t off = (size_t)(mb + r)*N + n;
          float c = acc[rt][ct][r] + bv;
          if (MODE == 1) Cf[off] = c + bf2f(residb[off]);
          if (MODE == 3) Cf[off] += c;
          if (MODE == 4){
            Cb[off] = f2bf(c);
            cs[ct] += c; cq[ct] += c*c;
          }
        }
      }
    }
  }

  if (MODE == 4){
    // reduce 128-row column sums within block -> psum/psq[mblock][n]
    __syncthreads();                 // As reads done in all waves
    float* wsm = (float*)As;         // [2][4 waves][64 cols] = 2 KB
    #pragma unroll
    for (int ct=0; ct<4; ++ct){
      float s = cs[ct], q = cq[ct];
      s += __shfl_xor(s,16,64); s += __shfl_xor(s,32,64);
      q += __shfl_xor(q,16,64); q += __shfl_xor(q,32,64);
      if (quad == 0){
        wsm[wv*64 + ct*16 + r16]       = s;
        wsm[256 + wv*64 + ct*16 + r16] = q;
      }
    }
    __syncthreads();
    if (t < 64){
      float s = wsm[t] + wsm[64+t] + wsm[128+t] + wsm[192+t];
      psum[(size_t)blockIdx.y*1024 + n0 + t] = s;
    } else if (t < 128){
      int c = t - 64;
      float q = wsm[256+c] + wsm[320+c] + wsm[384+c] + wsm[448+c];
      psq[(size_t)blockIdx.y*1024 + n0 + c] = q;
    }
  }
}

// ---------------- volw2: vol[b][k] from partials; sW2[b][n][k] = W2[n][k]*vol ----------------
__global__ __launch_bounds__(256) void volw2(
    const float* __restrict__ psum, const float* __restrict__ psq,
    const short* __restrict__ w2t, short* __restrict__ sw2)
{
  const int b = blockIdx.x>>2, kb = blockIdx.x&3;
  const int k = kb*256 + threadIdx.x;
  float s = 0.f, q = 0.f;
  #pragma unroll
  for (int m=0;m<8;++m){
    s += psum[(size_t)(b*8+m)*1024 + k];
    q += psq [(size_t)(b*8+m)*1024 + k];
  }
  float mean = s*(1.f/L_);
  float var  = q*(1.f/L_) - mean*mean;
  const float vol = sqrtf(fmaxf(var, 0.f));
  short* dst = sw2 + (size_t)b*262144 + k;
  const short* src = w2t + k;
  for (int n=0; n<256; ++n)
    dst[(size_t)n*1024] = f2bf(bf2f(src[(size_t)n*1024]) * vol);
}

// ---------------- MFMA ProbSparse attention v8: 8 waves, 40 KB LDS ----------------
// As v7 + po XOR-swizzle (2-way, free) + float2 final reads.
__global__ __launch_bounds__(512,8) void attn_mfma(
    const short* __restrict__ qkbf, const short* __restrict__ vT,
    short* __restrict__ ob)
{
  __shared__ __align__(16) short sc16[16*1024];   // 32 KB scores/weights
  __shared__ __align__(16) float po[8*256];       // 8 KB O partials
  const int t = threadIdx.x, wv = t>>6, lane = t&63;
  const int r16 = lane&15, quad = lane>>4;
  const int blk = blockIdx.x;
  const int bh = (blk & 7)*8 + ((blk>>3)&7);   // head pinned to one XCD
  const int qt = blk >> 6;

  bf16x8 aq = *(const bf16x8*)(qkbf + ((size_t)bh*1024 + qt*16 + r16)*32 + quad*8);
  const short* kb = qkbf + (size_t)(64 + bh)*1024*32;
  short* p0 = sc16 + quad*4096;        // rows quad*4..quad*4+3

  // ---- QK: 8 key-tiles per wave (keys wv*128..+127) ----
  #pragma unroll
  for (int g=0; g<2; ++g){
    bf16x8 bkb[4];
    #pragma unroll
    for (int j=0;j<4;++j)
      bkb[j] = *(const bf16x8*)(kb + (size_t)(wv*128 + (g*4+j)*16 + r16)*32 + quad*8);
    #pragma unroll
    for (int j=0;j<4;++j){
      f32x4 c = {0.f,0.f,0.f,0.f};
      c = __builtin_amdgcn_mfma_f32_16x16x32_bf16(aq, bkb[j], c, 0, 0, 0);
      const int keyq = (wv*128 + (g*4+j)*16 + r16) ^ ((quad&1)<<5);
      unsigned u01 = pk2bf(c[0], c[1]);
      unsigned u23 = pk2bf(c[2], c[3]);
      p0[keyq]               = (short)u01;          // r=0
      p0[1024 + (keyq ^ 8)]  = (short)(u01>>16);    // r=1
      p0[2048 + (keyq ^ 16)] = (short)u23;          // r=2
      p0[3072 + (keyq ^ 24)] = (short)(u23>>16);    // r=3
    }
  }
  __syncthreads();

  // ---- selection + softmax: wave wv owns rows 2wv, 2wv+1 (one pass) ----
  const float SC2 = 0.25500529485087056f;   // (1/sqrt(32)) * log2(e)
  {
    const int ra = wv*2;
    const int sa = (ra&7)<<3;                 // ra even
    short* pa = sc16 + ra*1024 + ((2*lane) ^ sa);
    short* pb = sc16 + (ra+1)*1024 + (((2*lane) ^ sa) ^ 8);
    float fa[16], fb[16];
    #pragma unroll
    for (int i=0;i<8;++i){
      unsigned wa = *(const unsigned*)(pa + i*128);
      unsigned wb = *(const unsigned*)(pb + i*128);
      fa[2*i]   = __uint_as_float(wa << 16);
      fa[2*i+1] = __uint_as_float(wa & 0xFFFF0000u);
      fb[2*i]   = __uint_as_float(wb << 16);
      fb[2*i+1] = __uint_as_float(wb & 0xFFFF0000u);
    }
    // fixed 16-step bit-descent over sortable-int candidates, float compares
    int loA = 0, loB = 0;
    #pragma unroll
    for (int bit = 15; bit >= 0; --bit){
      const int mA = loA | (1<<bit);
      const int mB = loB | (1<<bit);
      const float tA = kinvf(mA);   // wave-uniform -> SALU
      const float tB = kinvf(mB);
      int cA = 0, cB = 0;
      #pragma unroll
      for (int i=0;i<16;++i){
        cA += (int)__popcll(__ballot(fa[i] >= tA));
        cB += (int)__popcll(__ballot(fb[i] >= tB));
      }
      if (cA >= TOPK) loA = mA;
      if (cB >= TOPK) loB = mB;
    }
    const float thrA = kinvf(loA), thrB = kinvf(loB);
    float ea[16], eb[16];
    float suma = 0.f, sumb = 0.f;
    #pragma unroll
    for (int i=0;i<16;++i){
      ea[i] = (fa[i] >= thrA) ? exp2f(fa[i]*SC2) : 0.f;
      eb[i] = (fb[i] >= thrB) ? exp2f(fb[i]*SC2) : 0.f;
      suma += ea[i]; sumb += eb[i];
    }
    suma = wsum(suma); sumb = wsum(sumb);
    const float inva = 1.f/suma, invb = 1.f/sumb;
    #pragma unroll
    for (int i=0;i<8;++i){
      *(unsigned*)(pa + i*128) = pk2bf(ea[2*i]*inva, ea[2*i+1]*inva);
      *(unsigned*)(pb + i*128) = pk2bf(eb[2*i]*invb, eb[2*i+1]*invb);
    }
  }
  __syncthreads();

  // ---- PV: wave wv -> dim-half wv>>2 (16 dims), key-slice (wv&3)*256 ----
  const int dh = wv>>2, ks = (wv&3)*256;
  const short* vb = vT + (size_t)bh*32*1024 + (size_t)(dh*16 + r16)*1024;
  const int sA = (r16&7) << 3;         // s(row=r16)
  f32x4 oa = {0.f,0.f,0.f,0.f};
  #pragma unroll
  for (int j=0;j<8;++j){
    int k0 = ks + j*32;
    bf16x8 bv = *(const bf16x8*)(vb + k0 + quad*8);
    bf16x8 af = *(const bf16x8*)(sc16 + r16*1024 + ((k0 + quad*8) ^ sA));
    oa = __builtin_amdgcn_mfma_f32_16x16x32_bf16(af, bv, oa, 0, 0, 0);
  }
  // po write swizzled: bank-conflict-free (2-way max)
  #pragma unroll
  for (int r=0;r<4;++r){
    int row = quad*4 + r;
    po[wv*256 + ((row*16 + r16) ^ ((quad&1)<<4))] = oa[r];
  }
  __syncthreads();
  if (t < 256){
    int q = t>>4, d = (t&15)*2;        // d even; pair (d,d+1) in same half
    int h4 = (d>>4)*4;
    int idx = (q*16 + (d&15)) ^ (((q>>2)&1)<<4);
    float v0 = 0.f, v1 = 0.f;
    #pragma unroll
    for (int w=0;w<4;++w){
      float2 p = *(const float2*)(po + (h4+w)*256 + idx);
      v0 += p.x; v1 += p.y;
    }
    int b = bh>>3, hh = bh&7;
    size_t off = ((size_t)(b*1024 + qt*16 + q))*256 + hh*32 + d;
    *(unsigned*)(ob + off) = pk2bf(v0, v1);
  }
}

// ---------------- launch ----------------
extern "C" void kernel_launch(void* const* d_in, const int* in_sizes, int n_in,
                              void* d_out, int out_size, void* d_ws, size_t ws_size,
                              hipStream_t stream) {
  const float* x     = (const float*)d_in[0];
  const float* in_w  = (const float*)d_in[1];
  const float* in_b  = (const float*)d_in[2];
  const float* ln1_g = (const float*)d_in[3];
  const float* ln1_b = (const float*)d_in[4];
  const float* qkv_w = (const float*)d_in[5];
  const float* qkv_b = (const float*)d_in[6];
  const float* out_w = (const float*)d_in[7];
  const float* out_b = (const float*)d_in[8];
  const float* lna_g = (const float*)d_in[9];
  const float* lna_b = (const float*)d_in[10];
  const float* ln2_g = (const float*)d_in[11];
  const float* ln2_b = (const float*)d_in[12];
  const float* ff1_w = (const float*)d_in[13];
  const float* ff1_b = (const float*)d_in[14];
  const float* ff2_w = (const float*)d_in[15];
  const float* ff2_b = (const float*)d_in[16];
  const float* lnf_g = (const float*)d_in[17];
  const float* lnf_b = (const float*)d_in[18];
  float* out = (float*)d_out;

  // ws layout (~42.5 MB):
  //  h @0 8M | s2b @8M 4M | qkbf @12M 8M | vTb @20M 4M | ob_b @24M 4M
  //  f @12M 16M (aliases qkbf/vTb/ob_b — dead at ff1 time) | tb @28M 8M
  //  weights @36M (1.5M) | psum @38M 256K | psq @38.25M 256K | sw2 @38.5M 4M
  char* ws = (char*)d_ws;
  float* h     = (float*)(ws);
  short* s2b   = (short*)(ws + (size_t)( 8<<20));
  short* qkbf  = (short*)(ws + (size_t)(12<<20));
  short* vTb   = (short*)(ws + (size_t)(20<<20));
  short* ob_b  = (short*)(ws + (size_t)(24<<20));
  short* f     = (short*)(ws + (size_t)(12<<20));
  float* tb    = (float*)(ws + (size_t)(28<<20));
  short* qkvwT = (short*)(ws + (size_t)(36<<20));
  short* outwT = (short*)(ws + (size_t)(36<<20) + 393216);
  short* ff1wT = (short*)(ws + (size_t)(36<<20) + 393216 + 131072);
  short* ff2wT = (short*)(ws + (size_t)(36<<20) + 393216 + 131072 + 524288);
  float* psum  = (float*)(ws + (size_t)(38<<20));
  float* psq   = (float*)(ws + (size_t)(38<<20) + 262144);
  short* sw2   = (short*)(ws + (size_t)(38<<20) + 524288);

  embed_kernel<<<NR*64/256, 256, 0, stream>>>(x, in_w, in_b, h);
  wcvt<<< 768, 256, 0, stream>>>(qkv_w, qkvwT,  768, 8);
  wcvt<<< 256, 256, 0, stream>>>(out_w, outwT,  256, 8);
  wcvt<<<1024, 256, 0, stream>>>(ff1_w, ff1wT, 1024, 8);
  wcvt<<<1024, 256, 0, stream>>>(ff2_w, ff2wT,  256, 10);

  for (int layer = 0; layer < NLAYERS; ++layer){
    // s2b = bf16(LN1(h))
    ln_kernel<2><<<NR/4, 256, 0, stream>>>(h, ln1_g, ln1_b, nullptr, s2b);
    // qkv GEMM -> bf16 Q,K row-major + bf16 V^T
    {
      dim3 g(768/64, NR/128);
      mfma_gemm<0><<<g, 256, 0, stream>>>(s2b, qkvwT, qkv_b, nullptr,
                                          nullptr, qkbf, vTb, nullptr, nullptr,
                                          768, 256);
    }
    // ProbSparse attention -> ob bf16
    attn_mfma<<<64*64, 512, 0, stream>>>(qkbf, vTb, ob_b);
    // tb = ob @ out_w + out_b + s2 (fp32)
    {
      dim3 g(256/64, NR/128);
      mfma_gemm<1><<<g, 256, 0, stream>>>(ob_b, outwT, out_b, s2b,
                                          tb, nullptr, nullptr, nullptr, nullptr,
                                          256, 256);
    }
    // h += LN_a(tb); s2b = bf16(LN_2(h))
    lnln_kernel<<<NR/4, 256, 0, stream>>>(tb, lna_g, lna_b, ln2_g, ln2_b, h, s2b);
    // f = bf16(s2 @ ff1_w + ff1_b) + column sum/sumsq partials
    {
      dim3 g(1024/64, NR/128);
      mfma_gemm<4><<<g, 256, 0, stream>>>(s2b, ff1wT, ff1_b, nullptr,
                                          nullptr, f, nullptr, psum, psq,
                                          1024, 256);
    }
    // vol[b][k] + per-batch scaled W2
    volw2<<<32, 256, 0, stream>>>(psum, psq, ff2wT, sw2);
    // h += f @ (vol-scaled W2) + ff2_b
    {
      dim3 g(256/64, NR/128);
      mfma_gemm<3><<<g, 256, 0, stream>>>(f, sw2, ff2_b, nullptr,
                                          h, nullptr, nullptr, nullptr, nullptr,
                                          256, 1024);
    }
  }
  // out = LN_f(h)
  ln_kernel<0><<<NR/4, 256, 0, stream>>>(h, lnf_g, lnf_b, out, nullptr);
}

// Round 11
// 1156.268 us; speedup vs baseline: 1.0115x; 1.0115x over previous
//
#include <hip/hip_runtime.h>
#include <hip/hip_bf16.h>
#include <math.h>

#define D_MODEL 256
#define NH 8
#define DFF 1024
#define NLAYERS 6
#define B_ 8
#define L_ 1024
#define NR (B_*L_)          // 8192 rows
#define TOPK 256            // L/4
#define LNEPS 1e-5f

typedef __attribute__((ext_vector_type(8))) short bf16x8;
typedef __attribute__((ext_vector_type(4))) float f32x4;

// ---------------- helpers ----------------
__device__ __forceinline__ float wsum(float v){
  #pragma unroll
  for(int o=32;o>0;o>>=1) v += __shfl_xor(v,o,64);
  return v;
}
__device__ __forceinline__ short f2bf(float x){
  unsigned u = __float_as_uint(x);
  u += 0x7fffu + ((u>>16)&1u);   // RNE (finite inputs only)
  return (short)(u>>16);
}
__device__ __forceinline__ float bf2f(short s){
  return __uint_as_float(((unsigned)(unsigned short)s)<<16);
}
// packed 2x f32 -> 2x bf16 (v_cvt_pk_bf16_f32)
__device__ __forceinline__ unsigned pk2bf(float a, float b){
  __hip_bfloat162 h = __float22bfloat162_rn(make_float2(a,b));
  unsigned u; __builtin_memcpy(&u, &h, 4);
  return u;
}
// sortable 16-bit key -> float value
__device__ __forceinline__ float kinvf(int k){
  unsigned u = (k & 0x8000) ? ((unsigned)k ^ 0x8000u) : ((unsigned)k ^ 0xFFFFu);
  return __uint_as_float(u << 16);
}
// async global->LDS, 16B per lane (dest = wave-uniform base + lane*16)
__device__ __forceinline__ void g2l(const short* g, short* l){
  __builtin_amdgcn_global_load_lds(
      (const __attribute__((address_space(1))) unsigned int*)g,
      (__attribute__((address_space(3))) unsigned int*)l,
      16, 0, 0);
}

// ---------------- embed: h = x@in_w + in_b + pe ----------------
__global__ __launch_bounds__(256) void embed_kernel(
    const float* __restrict__ x, const float* __restrict__ in_w,
    const float* __restrict__ in_b, float* __restrict__ h)
{
  int tid = blockIdx.x*256 + threadIdx.x;
  int n  = tid >> 6;
  int d0 = (tid & 63) << 2;
  int l  = n & (L_-1);
  float x0 = x[2*n], x1 = x[2*n+1];
  const float kf = -0.07195578415606394f;   // -ln(10000)/128
  float pe[4];
  #pragma unroll
  for(int ii=0; ii<2; ++ii){
    int i = (d0>>1) + ii;
    float dv  = expf((float)i * kf);
    float ang = (float)l * dv;
    pe[2*ii]   = sinf(ang);
    pe[2*ii+1] = cosf(ang);
  }
  float4 w0 = *(const float4*)(in_w + d0);
  float4 w1 = *(const float4*)(in_w + D_MODEL + d0);
  float4 bb = *(const float4*)(in_b + d0);
  float4 o;
  o.x = x0*w0.x + x1*w1.x + bb.x + pe[0];
  o.y = x0*w0.y + x1*w1.y + bb.y + pe[1];
  o.z = x0*w0.z + x1*w1.z + bb.z + pe[2];
  o.w = x0*w0.w + x1*w1.w + bb.w + pe[3];
  *(float4*)(h + (size_t)n*D_MODEL + d0) = o;
}

// ---------------- all-weight convert+transpose in one dispatch ----------------
__global__ __launch_bounds__(256) void wcvt_all(
    const float* __restrict__ qkv_w, const float* __restrict__ out_w,
    const float* __restrict__ ff1_w, const float* __restrict__ ff2_w,
    short* __restrict__ qkvwT, short* __restrict__ outwT,
    short* __restrict__ ff1wT, short* __restrict__ ff2wT)
{
  const int bid = blockIdx.x;
  const float* W; short* WT; int N, kshift, base;
  if (bid < 768)      { W=qkv_w; WT=qkvwT; N=768;  kshift=8;  base=0; }
  else if (bid < 1024){ W=out_w; WT=outwT; N=256;  kshift=8;  base=768; }
  else if (bid < 2048){ W=ff1_w; WT=ff1wT; N=1024; kshift=8;  base=1024; }
  else                { W=ff2_w; WT=ff2wT; N=256;  kshift=10; base=2048; }
  int idx = (bid-base)*256 + threadIdx.x;
  int K = 1<<kshift;
  int n = idx >> kshift, k = idx & (K-1);
  WT[idx] = f2bf(W[(size_t)k*N + n]);
}

// ---------------- LayerNorm: wave per row ----------------
// OM: 0 = fp32 out, 2 = bf16 out only
template<int OM>
__global__ __launch_bounds__(256) void ln_kernel(
    const float* __restrict__ in, const float* __restrict__ g,
    const float* __restrict__ b, float* __restrict__ out,
    short* __restrict__ outb)
{
  int wave = threadIdx.x >> 6, lane = threadIdx.x & 63;
  int row = blockIdx.x*4 + wave;
  float4 v = ((const float4*)(in + (size_t)row*D_MODEL))[lane];
  float s  = v.x+v.y+v.z+v.w;
  float sq = v.x*v.x+v.y*v.y+v.z*v.z+v.w*v.w;
  s = wsum(s); sq = wsum(sq);
  float mean = s*(1.f/D_MODEL);
  float var  = sq*(1.f/D_MODEL) - mean*mean;
  float rstd = 1.f/sqrtf(var + LNEPS);
  float4 gv = ((const float4*)g)[lane];
  float4 bv = ((const float4*)b)[lane];
  float4 o;
  o.x = (v.x-mean)*rstd*gv.x + bv.x;
  o.y = (v.y-mean)*rstd*gv.y + bv.y;
  o.z = (v.z-mean)*rstd*gv.z + bv.z;
  o.w = (v.w-mean)*rstd*gv.w + bv.w;
  if (OM == 0){
    ((float4*)(out + (size_t)row*D_MODEL))[lane] = o;
  }
  if (OM == 2){
    uint2 pk; pk.x = pk2bf(o.x, o.y); pk.y = pk2bf(o.z, o.w);
    *(uint2*)(outb + (size_t)row*D_MODEL + lane*4) = pk;
  }
}

// ---------------- fused: h += LN_a(tbb:bf16); s2b = bf16(LN_2(h)) ----------------
__global__ __launch_bounds__(256) void lnln_kernel(
    const short* __restrict__ tbb,
    const float* __restrict__ ga, const float* __restrict__ ba,
    const float* __restrict__ g2, const float* __restrict__ b2,
    float* __restrict__ h, short* __restrict__ s2b)
{
  int wave = threadIdx.x >> 6, lane = threadIdx.x & 63;
  int row = blockIdx.x*4 + wave;
  uint2 w = *(const uint2*)(tbb + (size_t)row*D_MODEL + lane*4);
  float4 v;
  v.x = __uint_as_float(w.x << 16);
  v.y = __uint_as_float(w.x & 0xFFFF0000u);
  v.z = __uint_as_float(w.y << 16);
  v.w = __uint_as_float(w.y & 0xFFFF0000u);
  float s  = v.x+v.y+v.z+v.w;
  float sq = v.x*v.x+v.y*v.y+v.z*v.z+v.w*v.w;
  s = wsum(s); sq = wsum(sq);
  float mean = s*(1.f/D_MODEL);
  float var  = sq*(1.f/D_MODEL) - mean*mean;
  float rstd = 1.f/sqrtf(var + LNEPS);
  float4 gv = ((const float4*)ga)[lane];
  float4 bv = ((const float4*)ba)[lane];
  float4* hp = (float4*)(h + (size_t)row*D_MODEL) + lane;
  float4 hv = *hp;
  float4 hn;
  hn.x = hv.x + (v.x-mean)*rstd*gv.x + bv.x;
  hn.y = hv.y + (v.y-mean)*rstd*gv.y + bv.y;
  hn.z = hv.z + (v.z-mean)*rstd*gv.z + bv.z;
  hn.w = hv.w + (v.w-mean)*rstd*gv.w + bv.w;
  *hp = hn;
  float s2  = hn.x+hn.y+hn.z+hn.w;
  float sq2 = hn.x*hn.x+hn.y*hn.y+hn.z*hn.z+hn.w*hn.w;
  s2 = wsum(s2); sq2 = wsum(sq2);
  float m2 = s2*(1.f/D_MODEL);
  float v2 = sq2*(1.f/D_MODEL) - m2*m2;
  float r2 = 1.f/sqrtf(v2 + LNEPS);
  float4 g2v = ((const float4*)g2)[lane];
  float4 b2v = ((const float4*)b2)[lane];
  uint2 pk;
  pk.x = pk2bf((hn.x-m2)*r2*g2v.x + b2v.x, (hn.y-m2)*r2*g2v.y + b2v.y);
  pk.y = pk2bf((hn.z-m2)*r2*g2v.z + b2v.z, (hn.w-m2)*r2*g2v.w + b2v.w);
  *(uint2*)(s2b + (size_t)row*D_MODEL + lane*4) = pk;
}

// ---------------- bf16 MFMA GEMM: 128x64 tile, BK=32 (measured-best) ----------------
// MODE 0: qkv epilogue (Q/K row-major bf16 + V^T bf16)
// MODE 1: Cb = bf16(acc + bias + bf2f(residb))   (bf16 out)
// MODE 2: Cb = bf16(acc + bias)
// MODE 3: Cf += acc + bias                       (fp32 accumulate into h)
template<int MODE>
__global__ __launch_bounds__(256) void mfma_gemm(
    const short* __restrict__ A, const short* __restrict__ BT,
    const float* __restrict__ bias, const short* __restrict__ residb,
    float* __restrict__ Cf, short* __restrict__ Cb, short* __restrict__ Vt,
    int N, int K)
{
  __shared__ __align__(16) short As[128*32];   // 8 KB [m][k]
  __shared__ __align__(16) short Bs[64*32];    // 4 KB [n][k]
  const int t = threadIdx.x, wv = t>>6, lane = t&63;
  const int r16 = lane&15, quad = lane>>4;
  const int m0 = blockIdx.y*128, n0 = blockIdx.x*64;
  const int ia0 = wv*128 + lane, ia1 = ia0 + 64;
  const int ib  = wv*64 + lane;
  const short* Ab = A  + (size_t)m0*K;
  const short* Bb = BT + (size_t)n0*K;
  const f32x4 z = {0.f,0.f,0.f,0.f};
  f32x4 acc[2][4];
  #pragma unroll
  for (int i=0;i<2;++i)
    #pragma unroll
    for (int j=0;j<4;++j) acc[i][j] = z;

  for (int k0 = 0; k0 < K; k0 += 32){
    __syncthreads();
    g2l(Ab + (size_t)(ia0>>2)*K + k0 + (ia0&3)*8, As + ia0*8);
    g2l(Ab + (size_t)(ia1>>2)*K + k0 + (ia1&3)*8, As + ia1*8);
    g2l(Bb + (size_t)(ib>>2)*K  + k0 + (ib&3)*8,  Bs + ib*8);
    __syncthreads();
    bf16x8 af0 = *(const bf16x8*)(As + ((wv*32      + r16)*32 + quad*8));
    bf16x8 af1 = *(const bf16x8*)(As + ((wv*32 + 16 + r16)*32 + quad*8));
    bf16x8 bf[4];
    #pragma unroll
    for (int ct=0; ct<4; ++ct)
      bf[ct] = *(const bf16x8*)(Bs + ((ct*16 + r16)*32 + quad*8));
    #pragma unroll
    for (int ct=0; ct<4; ++ct){
      acc[0][ct] = __builtin_amdgcn_mfma_f32_16x16x32_bf16(af0, bf[ct], acc[0][ct], 0,0,0);
      acc[1][ct] = __builtin_amdgcn_mfma_f32_16x16x32_bf16(af1, bf[ct], acc[1][ct], 0,0,0);
    }
  }

  #pragma unroll
  for (int rt=0; rt<2; ++rt){
    const int mb = m0 + wv*32 + rt*16 + quad*4;
    #pragma unroll
    for (int ct=0; ct<4; ++ct){
      const int n = n0 + ct*16 + r16;
      const float bv = bias[n];
      if (MODE == 0){
        if (n < 512){                    // Q or K: qkbf[region*64+bh][l][d]
          int region = n>>8, hh = (n>>5)&7, d = n&31;
          #pragma unroll
          for (int r=0;r<4;++r){
            int l = mb + r;
            size_t base = (((size_t)(region*64 + (l>>10)*8 + hh))*1024 + (l&1023))*32 + d;
            Cb[base] = f2bf(acc[rt][ct][r] + bv);
          }
        } else {                         // V transposed: vT[bh][d][l]
          int dv = n - 512, hh = dv>>5, d = dv&31;
          int b = mb>>10, lloc = mb&1023;
          size_t base = (((size_t)(b*8 + hh))*32 + d)*1024 + lloc;
          uint2 pk;
          pk.x = pk2bf(acc[rt][ct][0] + bv, acc[rt][ct][1] + bv);
          pk.y = pk2bf(acc[rt][ct][2] + bv, acc[rt][ct][3] + bv);
          *(uint2*)(Vt + base) = pk;
        }
      } else {
        #pragma unroll
        for (int r=0;r<4;++r){
          size_t off = (size_t)(mb + r)*N + n;
          float c = acc[rt][ct][r] + bv;
          if (MODE == 1) Cb[off] = f2bf(c + bf2f(residb[off]));
          if (MODE == 2) Cb[off] = f2bf(c);
          if (MODE == 3) Cf[off] += c;
        }
      }
    }
  }
}

// ---------------- MFMA ProbSparse attention v8: 8 waves, 40 KB LDS ----------------
// 16 q-rows/block, 512 thr. QK 8 tiles/wave; selection 2 rows/wave single-pass
// float-domain 16-step bit-descent (thresholds forced scalar); PV dim-half
// split; po XOR-swizzled. 40 KB LDS -> 4 blocks x 8 waves = 32 waves/CU.
__global__ __launch_bounds__(512,8) void attn_mfma(
    const short* __restrict__ qkbf, const short* __restrict__ vT,
    short* __restrict__ ob)
{
  __shared__ __align__(16) short sc16[16*1024];   // 32 KB scores/weights
  __shared__ __align__(16) float po[8*256];       // 8 KB O partials
  const int t = threadIdx.x, wv = t>>6, lane = t&63;
  const int r16 = lane&15, quad = lane>>4;
  const int blk = blockIdx.x;
  const int bh = (blk & 7)*8 + ((blk>>3)&7);   // head pinned to one XCD
  const int qt = blk >> 6;

  bf16x8 aq = *(const bf16x8*)(qkbf + ((size_t)bh*1024 + qt*16 + r16)*32 + quad*8);
  const short* kb = qkbf + (size_t)(64 + bh)*1024*32;
  short* p0 = sc16 + quad*4096;        // rows quad*4..quad*4+3

  // ---- QK: 8 key-tiles per wave (keys wv*128..+127) ----
  #pragma unroll
  for (int g=0; g<2; ++g){
    bf16x8 bkb[4];
    #pragma unroll
    for (int j=0;j<4;++j)
      bkb[j] = *(const bf16x8*)(kb + (size_t)(wv*128 + (g*4+j)*16 + r16)*32 + quad*8);
    #pragma unroll
    for (int j=0;j<4;++j){
      f32x4 c = {0.f,0.f,0.f,0.f};
      c = __builtin_amdgcn_mfma_f32_16x16x32_bf16(aq, bkb[j], c, 0, 0, 0);
      const int keyq = (wv*128 + (g*4+j)*16 + r16) ^ ((quad&1)<<5);
      unsigned u01 = pk2bf(c[0], c[1]);
      unsigned u23 = pk2bf(c[2], c[3]);
      p0[keyq]               = (short)u01;          // r=0
      p0[1024 + (keyq ^ 8)]  = (short)(u01>>16);    // r=1
      p0[2048 + (keyq ^ 16)] = (short)u23;          // r=2
      p0[3072 + (keyq ^ 24)] = (short)(u23>>16);    // r=3
    }
  }
  __syncthreads();

  // ---- selection + softmax: wave wv owns rows 2wv, 2wv+1 (one pass) ----
  const float SC2 = 0.25500529485087056f;   // (1/sqrt(32)) * log2(e)
  {
    const int ra = wv*2;
    const int sa = (ra&7)<<3;                 // ra even
    short* pa = sc16 + ra*1024 + ((2*lane) ^ sa);
    short* pb = sc16 + (ra+1)*1024 + (((2*lane) ^ sa) ^ 8);
    float fa[16], fb[16];
    #pragma unroll
    for (int i=0;i<8;++i){
      unsigned wa = *(const unsigned*)(pa + i*128);
      unsigned wb = *(const unsigned*)(pb + i*128);
      fa[2*i]   = __uint_as_float(wa << 16);
      fa[2*i+1] = __uint_as_float(wa & 0xFFFF0000u);
      fb[2*i]   = __uint_as_float(wb << 16);
      fb[2*i+1] = __uint_as_float(wb & 0xFFFF0000u);
    }
    // fixed 16-step bit-descent; thresholds forced to SGPR
    int loA = 0, loB = 0;
    #pragma unroll
    for (int bit = 15; bit >= 0; --bit){
      const int mA = loA | (1<<bit);
      const int mB = loB | (1<<bit);
      const float tA = __uint_as_float(
          __builtin_amdgcn_readfirstlane(__float_as_uint(kinvf(mA))));
      const float tB = __uint_as_float(
          __builtin_amdgcn_readfirstlane(__float_as_uint(kinvf(mB))));
      int cA = 0, cB = 0;
      #pragma unroll
      for (int i=0;i<16;++i){
        cA += (int)__popcll(__ballot(fa[i] >= tA));
        cB += (int)__popcll(__ballot(fb[i] >= tB));
      }
      if (cA >= TOPK) loA = mA;
      if (cB >= TOPK) loB = mB;
    }
    const float thrA = kinvf(loA), thrB = kinvf(loB);
    float ea[16], eb[16];
    float suma = 0.f, sumb = 0.f;
    #pragma unroll
    for (int i=0;i<16;++i){
      ea[i] = (fa[i] >= thrA) ? exp2f(fa[i]*SC2) : 0.f;
      eb[i] = (fb[i] >= thrB) ? exp2f(fb[i]*SC2) : 0.f;
      suma += ea[i]; sumb += eb[i];
    }
    suma = wsum(suma); sumb = wsum(sumb);
    const float inva = 1.f/suma, invb = 1.f/sumb;
    #pragma unroll
    for (int i=0;i<8;++i){
      *(unsigned*)(pa + i*128) = pk2bf(ea[2*i]*inva, ea[2*i+1]*inva);
      *(unsigned*)(pb + i*128) = pk2bf(eb[2*i]*invb, eb[2*i+1]*invb);
    }
  }
  __syncthreads();

  // ---- PV: wave wv -> dim-half wv>>2 (16 dims), key-slice (wv&3)*256 ----
  const int dh = wv>>2, ks = (wv&3)*256;
  const short* vb = vT + (size_t)bh*32*1024 + (size_t)(dh*16 + r16)*1024;
  const int sA = (r16&7) << 3;         // s(row=r16)
  f32x4 oa = {0.f,0.f,0.f,0.f};
  #pragma unroll
  for (int j=0;j<8;++j){
    int k0 = ks + j*32;
    bf16x8 bv = *(const bf16x8*)(vb + k0 + quad*8);
    bf16x8 af = *(const bf16x8*)(sc16 + r16*1024 + ((k0 + quad*8) ^ sA));
    oa = __builtin_amdgcn_mfma_f32_16x16x32_bf16(af, bv, oa, 0, 0, 0);
  }
  // po write swizzled (2-way max)
  #pragma unroll
  for (int r=0;r<4;++r){
    int row = quad*4 + r;
    po[wv*256 + ((row*16 + r16) ^ ((quad&1)<<4))] = oa[r];
  }
  __syncthreads();
  if (t < 256){
    int q = t>>4, d = (t&15)*2;        // d even; pair (d,d+1) in same half
    int h4 = (d>>4)*4;
    int idx = (q*16 + (d&15)) ^ (((q>>2)&1)<<4);
    float v0 = 0.f, v1 = 0.f;
    #pragma unroll
    for (int w=0;w<4;++w){
      float2 p = *(const float2*)(po + (h4+w)*256 + idx);
      v0 += p.x; v1 += p.y;
    }
    int b = bh>>3, hh = bh&7;
    size_t off = ((size_t)(b*1024 + qt*16 + q))*256 + hh*32 + d;
    *(unsigned*)(ob + off) = pk2bf(v0, v1);
  }
}

// ---------------- Volatilite: f *= std_L(f), in place (bf16) ----------------
__global__ __launch_bounds__(512) void vol_scale(short* __restrict__ f)
{
  __shared__ float ps[8][64], pq[8][64], vs[64];
  int b = blockIdx.x >> 4, cb = blockIdx.x & 15;
  int cl = threadIdx.x & 63, sl = threadIdx.x >> 6;   // 8 waves x 128 L each
  int col = cb*64 + cl;
  short* fb = f + (size_t)b*L_*DFF + col;
  float s = 0.f, sq = 0.f;
  for (int l = sl*128; l < sl*128+128; ++l){
    float v = bf2f(fb[(size_t)l*DFF]);
    s += v; sq += v*v;
  }
  ps[sl][cl] = s; pq[sl][cl] = sq;
  __syncthreads();
  if (threadIdx.x < 64){
    float st=0.f, qt=0.f;
    #pragma unroll
    for (int i=0;i<8;++i){ st += ps[i][cl]; qt += pq[i][cl]; }
    float mean = st*(1.f/L_);
    float var  = qt*(1.f/L_) - mean*mean;
    vs[cl] = sqrtf(fmaxf(var, 0.f));
  }
  __syncthreads();
  float vv = vs[cl];
  for (int l = sl*128; l < sl*128+128; ++l){
    size_t o = (size_t)l*DFF;
    fb[o] = f2bf(bf2f(fb[o]) * vv);
  }
}

// ---------------- launch ----------------
extern "C" void kernel_launch(void* const* d_in, const int* in_sizes, int n_in,
                              void* d_out, int out_size, void* d_ws, size_t ws_size,
                              hipStream_t stream) {
  const float* x     = (const float*)d_in[0];
  const float* in_w  = (const float*)d_in[1];
  const float* in_b  = (const float*)d_in[2];
  const float* ln1_g = (const float*)d_in[3];
  const float* ln1_b = (const float*)d_in[4];
  const float* qkv_w = (const float*)d_in[5];
  const float* qkv_b = (const float*)d_in[6];
  const float* out_w = (const float*)d_in[7];
  const float* out_b = (const float*)d_in[8];
  const float* lna_g = (const float*)d_in[9];
  const float* lna_b = (const float*)d_in[10];
  const float* ln2_g = (const float*)d_in[11];
  const float* ln2_b = (const float*)d_in[12];
  const float* ff1_w = (const float*)d_in[13];
  const float* ff1_b = (const float*)d_in[14];
  const float* ff2_w = (const float*)d_in[15];
  const float* ff2_b = (const float*)d_in[16];
  const float* lnf_g = (const float*)d_in[17];
  const float* lnf_b = (const float*)d_in[18];
  float* out = (float*)d_out;

  // ws layout (~37.6 MB):
  //  h @0 8M | s2b @8M 4M | qkbf @12M 8M | vTb @20M 4M | ob_b @24M 4M
  //  f @12M 16M (aliases qkbf/vTb/ob_b — dead at ff1 time) | tbb @28M 4M
  //  weights @36M: qkv 384K + out 128K + ff1 512K + ff2 512K
  char* ws = (char*)d_ws;
  float* h     = (float*)(ws);
  short* s2b   = (short*)(ws + (size_t)( 8<<20));
  short* qkbf  = (short*)(ws + (size_t)(12<<20));
  short* vTb   = (short*)(ws + (size_t)(20<<20));
  short* ob_b  = (short*)(ws + (size_t)(24<<20));
  short* f     = (short*)(ws + (size_t)(12<<20));
  short* tbb   = (short*)(ws + (size_t)(28<<20));
  short* qkvwT = (short*)(ws + (size_t)(36<<20));
  short* outwT = (short*)(ws + (size_t)(36<<20) + 393216);
  short* ff1wT = (short*)(ws + (size_t)(36<<20) + 393216 + 131072);
  short* ff2wT = (short*)(ws + (size_t)(36<<20) + 393216 + 131072 + 524288);

  embed_kernel<<<NR*64/256, 256, 0, stream>>>(x, in_w, in_b, h);
  wcvt_all<<<3072, 256, 0, stream>>>(qkv_w, out_w, ff1_w, ff2_w,
                                     qkvwT, outwT, ff1wT, ff2wT);

  for (int layer = 0; layer < NLAYERS; ++layer){
    // s2b = bf16(LN1(h))
    ln_kernel<2><<<NR/4, 256, 0, stream>>>(h, ln1_g, ln1_b, nullptr, s2b);
    // qkv GEMM -> bf16 Q,K row-major + bf16 V^T
    {
      dim3 g(768/64, NR/128);
      mfma_gemm<0><<<g, 256, 0, stream>>>(s2b, qkvwT, qkv_b, nullptr,
                                          nullptr, qkbf, vTb, 768, 256);
    }
    // ProbSparse attention -> ob bf16
    attn_mfma<<<64*64, 512, 0, stream>>>(qkbf, vTb, ob_b);
    // tbb = bf16(ob @ out_w + out_b + s2)
    {
      dim3 g(256/64, NR/128);
      mfma_gemm<1><<<g, 256, 0, stream>>>(ob_b, outwT, out_b, s2b,
                                          nullptr, tbb, nullptr, 256, 256);
    }
    // h += LN_a(tbb); s2b = bf16(LN_2(h))
    lnln_kernel<<<NR/4, 256, 0, stream>>>(tbb, lna_g, lna_b, ln2_g, ln2_b, h, s2b);
    // f = bf16(s2 @ ff1_w + ff1_b)
    {
      dim3 g(1024/64, NR/128);
      mfma_gemm<2><<<g, 256, 0, stream>>>(s2b, ff1wT, ff1_b, nullptr,
                                          nullptr, f, nullptr, 1024, 256);
    }
    // f *= std_L(f) in place
    vol_scale<<<B_*16, 512, 0, stream>>>(f);
    // h += f @ ff2_w + ff2_b
    {
      dim3 g(256/64, NR/128);
      mfma_gemm<3><<<g, 256, 0, stream>>>(f, ff2wT, ff2_b, nullptr,
                                          h, nullptr, nullptr, 256, 1024);
    }
  }
  // out = LN_f(h)
  ln_kernel<0><<<NR/4, 256, 0, stream>>>(h, lnf_g, lnf_b, out, nullptr);
}